// Round 1
// baseline (852.939 us; speedup 1.0000x reference)
//
#include <hip/hip_runtime.h>
#include <hip/hip_bf16.h>

// ---- sizes ----
// x: [2][128][256][128] f32, out: same
// Wtab: [s*2+conv][8 r][1152 k=ci*9+tap][128 co] f32
#define TBL (8*1152*128)

// ============================================================
// Kernel 1: per-(s,conv,m) MLP -> embedding e (128) -> h_in (64x128)
// grid 16 blocks, 256 threads
// ============================================================
__global__ __launch_bounds__(256) void embed_kernel(
    const float* __restrict__ seidel,
    const float* __restrict__ m1W1, const float* __restrict__ m1b1,
    const float* __restrict__ m1W2, const float* __restrict__ m1b2,
    const float* __restrict__ m2W1, const float* __restrict__ m2b1,
    const float* __restrict__ m2W2, const float* __restrict__ m2b2,
    const float* __restrict__ hw2, const float* __restrict__ hb2,
    float* __restrict__ hin)
{
    int combo = blockIdx.x;                 // (s*2+conv)*4 + m
    int s = combo >> 3, conv = (combo >> 2) & 1, m = combo & 3;
    const float* W1 = conv ? m2W1 : m1W1;   // (4,48,128)
    const float* b1 = conv ? m2b1 : m1b1;
    const float* W2 = conv ? m2W2 : m1W2;   // (4,128,128)
    const float* b2 = conv ? m2b2 : m1b2;
    __shared__ float zs[48], hbuf[128], ebuf[128];
    int tid = threadIdx.x;
    if (tid < 48) zs[tid] = seidel[s*48 + tid];
    __syncthreads();
    if (tid < 128) {
        float a = b1[m*128 + tid];
        for (int i = 0; i < 48; ++i) a += zs[i] * W1[(m*48 + i)*128 + tid];
        hbuf[tid] = fmaxf(a, 0.f);
    }
    __syncthreads();
    if (tid < 128) {
        float a = b2[m*128 + tid];
        for (int i = 0; i < 128; ++i) a += hbuf[i] * W2[(m*128 + i)*128 + tid];
        ebuf[tid] = fmaxf(a, 0.f);
    }
    __syncthreads();
    // h_in[a][d] = e @ hyp_w2 + hyp_b2 ; a=0..63, d=0..127
    int j = tid & 127, half = tid >> 7;     // j=d, half selects a-range
    float acc[32];
    #pragma unroll
    for (int t = 0; t < 32; ++t) acc[t] = hb2[(half*32 + t)*128 + j];
    for (int i = 0; i < 128; ++i) {
        float e = ebuf[i];
        #pragma unroll
        for (int t = 0; t < 32; ++t)
            acc[t] += e * hw2[(size_t)i*8192 + (size_t)(half*32 + t)*128 + j];
    }
    #pragma unroll
    for (int t = 0; t < 32; ++t)
        hin[(size_t)combo*8192 + (size_t)(half*32 + t)*128 + j] = acc[t];
}

// ============================================================
// Kernel 2: h_fin = h_in @ hyp_w1 + hyp_b1, scattered into Wtab with
// the block-assemble mapping.  grid (18, 16), 256 threads.
// j = b*72 + r*9 + tap ;  co = (m>>1)*64 + a ; ci = (m&1)*64 + b
// ============================================================
__global__ __launch_bounds__(256) void hfin_kernel(
    const float* __restrict__ hin, const float* __restrict__ hw1,
    const float* __restrict__ hb1, float* __restrict__ wtab)
{
    int combo = blockIdx.y;
    int tid = threadIdx.x;
    int j = blockIdx.x*256 + tid;           // < 4608
    __shared__ float hl[64][128];
    const float* hs = hin + (size_t)combo*8192;
    for (int i = tid; i < 8192; i += 256)
        hl[i >> 7][i & 127] = hs[i];
    __syncthreads();
    float acc[64];
    float bias = hb1[j];
    #pragma unroll
    for (int a = 0; a < 64; ++a) acc[a] = bias;
    for (int k = 0; k < 128; k += 4) {
        float w0 = hw1[(size_t)(k+0)*4608 + j];
        float w1 = hw1[(size_t)(k+1)*4608 + j];
        float w2 = hw1[(size_t)(k+2)*4608 + j];
        float w3 = hw1[(size_t)(k+3)*4608 + j];
        #pragma unroll
        for (int a = 0; a < 64; ++a) {
            float4 h4 = *(const float4*)&hl[a][k];
            acc[a] += h4.x*w0 + h4.y*w1 + h4.z*w2 + h4.w*w3;
        }
    }
    int b = j/72, rem = j%72, r = rem/9, tap = rem%9;
    int s = combo >> 3, conv = (combo >> 2) & 1, m = combo & 3;
    int ci = (m & 1)*64 + b;
    int krow = ci*9 + tap;
    float* dst = wtab + (((size_t)(s*2 + conv)*8 + r)*1152 + krow)*128 + (m >> 1)*64;
    #pragma unroll
    for (int a = 0; a < 64; a += 4) {
        float4 v = make_float4(acc[a], acc[a+1], acc[a+2], acc[a+3]);
        *(float4*)&dst[a] = v;
    }
}

// ============================================================
// Kernel 3: transpose [sc][256 H][128 W] -> [sc][128 W][256 H]
// grid (4, 8, 256), block (32, 8)
// ============================================================
__global__ void transpose_kernel(const float* __restrict__ in, float* __restrict__ out)
{
    __shared__ float tile[32][33];
    int sc = blockIdx.z;
    int h0 = blockIdx.y*32, w0 = blockIdx.x*32;
    int tx = threadIdx.x, ty = threadIdx.y;
    const float* src = in + ((size_t)sc*256 + h0)*128 + w0;
    #pragma unroll
    for (int i = 0; i < 4; ++i) tile[ty + i*8][tx] = src[(size_t)(ty + i*8)*128 + tx];
    __syncthreads();
    float* dst = out + ((size_t)sc*128 + w0)*256 + h0;
    #pragma unroll
    for (int i = 0; i < 4; ++i) dst[(size_t)(ty + i*8)*256 + tx] = tile[tx][ty + i*8];
}

// ============================================================
// Kernel 4: LRI conv + BN(eval) + ReLU.
// Input transposed [s][128 c][128 W][256 H]; weight table per (s,conv).
// One block = (sample s, column w, 64-row h-tile); 256 threads.
// Thread = (cg 0..31 -> 4 co, hg 0..7 -> 8 h).
// OUT_STD=0: write transposed [s][co][W][H]; OUT_STD=1: standard [s][co][H][W].
// ============================================================
template<int OUT_STD>
__global__ __launch_bounds__(256) void conv_kernel(
    const float* __restrict__ xin,
    const float* __restrict__ wtab,
    int conv,
    const float* __restrict__ bng, const float* __restrict__ bnb,
    float* __restrict__ out)
{
    int w = blockIdx.x, ht = blockIdx.y, s = blockIdx.z;
    int hbase = ht*64;
    const float* xs = xin + (size_t)s*128*128*256;
    const float* wt = wtab + (size_t)(s*2 + conv)*TBL;

    // radius interpolation factors for this column
    float fsrc = (w + 0.5f)*0.0625f - 0.5f;
    fsrc = fminf(fmaxf(fsrc, 0.f), 7.f);
    int r0 = (int)fsrc;
    int r1 = min(r0 + 1, 7);
    float t = fsrc - (float)r0;

    __shared__ float wl[72][128];   // interpolated weights, k-local x co
    __shared__ float pat[72][64];   // di/dj-shifted input patches, k-local x h

    int tid = threadIdx.x;
    int cg = tid & 31, hg = tid >> 5;
    float acc[4][8];
    #pragma unroll
    for (int c = 0; c < 4; ++c)
        #pragma unroll
        for (int h = 0; h < 8; ++h) acc[c][h] = 0.f;

    for (int cb = 0; cb < 16; ++cb) {       // 8 input channels per iter
        __syncthreads();
        // ---- stage interpolated weights: 72 k x 128 co ----
        const float* p0 = wt + ((size_t)r0*1152 + cb*72)*128;
        const float* p1 = wt + ((size_t)r1*1152 + cb*72)*128;
        #pragma unroll
        for (int i = 0; i < 9; ++i) {
            int idx = tid + i*256;          // float4 units, 2304 total
            int k = idx >> 5, c4 = (idx & 31)*4;
            float4 a = *(const float4*)&p0[k*128 + c4];
            float4 b = *(const float4*)&p1[k*128 + c4];
            float4 v = make_float4(a.x + t*(b.x - a.x), a.y + t*(b.y - a.y),
                                   a.z + t*(b.z - a.z), a.w + t*(b.w - a.w));
            *(float4*)&wl[k][c4] = v;
        }
        // ---- stage patches: pat[ci_l*9+di*3+dj][hh] = x[ci][h+di-1 (circ)][w+dj-1 (zero)] ----
        #pragma unroll
        for (int i = 0; i < 18; ++i) {
            int idx = tid + i*256;          // 4608 total
            int k = idx >> 6, hh = idx & 63;
            int ci = k/9, tap = k - ci*9;
            int di = tap/3, dj = tap - di*3;
            int wsrc = w + dj - 1;
            float v = 0.f;
            if (wsrc >= 0 && wsrc < 128) {
                int hsrc = (hbase + hh + di - 1 + 256) & 255;
                v = xs[((size_t)(cb*8 + ci)*128 + wsrc)*256 + hsrc];
            }
            pat[k][hh] = v;
        }
        __syncthreads();
        // ---- accumulate: 72 k x (4 co x 8 h) ----
        #pragma unroll 4
        for (int k = 0; k < 72; ++k) {
            float4 wv = *(const float4*)&wl[k][cg*4];
            float4 q0 = *(const float4*)&pat[k][hg*8];
            float4 q1 = *(const float4*)&pat[k][hg*8 + 4];
            float wc[4] = {wv.x, wv.y, wv.z, wv.w};
            float pv[8] = {q0.x, q0.y, q0.z, q0.w, q1.x, q1.y, q1.z, q1.w};
            #pragma unroll
            for (int c = 0; c < 4; ++c)
                #pragma unroll
                for (int h = 0; h < 8; ++h)
                    acc[c][h] += wc[c]*pv[h];
        }
    }
    // ---- BN + ReLU + store ----
    int co0 = cg*4;
    float rs = rsqrtf(1.f + 1e-5f);
    #pragma unroll
    for (int c = 0; c < 4; ++c) {
        int co = co0 + c;
        float sc = bng[co]*rs, bt = bnb[co];
        float vals[8];
        #pragma unroll
        for (int h = 0; h < 8; ++h) vals[h] = fmaxf(acc[c][h]*sc + bt, 0.f);
        if (OUT_STD) {
            size_t base = ((size_t)(s*128 + co)*256 + hbase + hg*8)*128 + w;
            #pragma unroll
            for (int h = 0; h < 8; ++h) out[base + (size_t)h*128] = vals[h];
        } else {
            float* d = out + ((size_t)(s*128 + co)*128 + w)*256 + hbase + hg*8;
            *(float4*)&d[0] = make_float4(vals[0], vals[1], vals[2], vals[3]);
            *(float4*)&d[4] = make_float4(vals[4], vals[5], vals[6], vals[7]);
        }
    }
}

// ============================================================
extern "C" void kernel_launch(void* const* d_in, const int* in_sizes, int n_in,
                              void* d_out, int out_size, void* d_ws, size_t ws_size,
                              hipStream_t stream) {
    const float* x      = (const float*)d_in[0];
    const float* seidel = (const float*)d_in[1];
    const float* m1W1 = (const float*)d_in[2];
    const float* m1b1 = (const float*)d_in[3];
    const float* m1W2 = (const float*)d_in[4];
    const float* m1b2 = (const float*)d_in[5];
    const float* m2W1 = (const float*)d_in[6];
    const float* m2b1 = (const float*)d_in[7];
    const float* m2W2 = (const float*)d_in[8];
    const float* m2b2 = (const float*)d_in[9];
    const float* hw2  = (const float*)d_in[10];
    const float* hb2  = (const float*)d_in[11];
    const float* hw1  = (const float*)d_in[12];
    const float* hb1  = (const float*)d_in[13];
    const float* bn1g = (const float*)d_in[14];
    const float* bn1b = (const float*)d_in[15];
    const float* bn2g = (const float*)d_in[16];
    const float* bn2b = (const float*)d_in[17];
    float* outp = (float*)d_out;

    float* ws   = (float*)d_ws;
    float* hin  = ws;                           // 16*8192           = 131072 f
    float* wtab = ws + 131072;                  // 4*8*1152*128     = 4718592 f
    float* x_t  = wtab + (size_t)4*TBL;         // 2*128*128*256    = 8388608 f
    float* y1t  = x_t + (size_t)8388608;        // 8388608 f

    embed_kernel<<<16, 256, 0, stream>>>(seidel, m1W1, m1b1, m1W2, m1b2,
                                         m2W1, m2b1, m2W2, m2b2, hw2, hb2, hin);
    hfin_kernel<<<dim3(18, 16), 256, 0, stream>>>(hin, hw1, hb1, wtab);
    transpose_kernel<<<dim3(4, 8, 256), dim3(32, 8), 0, stream>>>(x, x_t);
    conv_kernel<0><<<dim3(128, 4, 2), 256, 0, stream>>>(x_t, wtab, 0, bn1g, bn1b, y1t);
    conv_kernel<1><<<dim3(128, 4, 2), 256, 0, stream>>>(y1t, wtab, 1, bn2g, bn2b, outp);
}

// Round 2
// 288.212 us; speedup vs baseline: 2.9594x; 2.9594x over previous
//
#include <hip/hip_runtime.h>
#include <hip/hip_bf16.h>

typedef _Float16 f16;
typedef _Float16 half8 __attribute__((ext_vector_type(8)));
typedef float floatx16 __attribute__((ext_vector_type(16)));

#define STRIDE 40   // f16 elems per padded LDS row (80 B, 16B-aligned, bank-uniform)

// ============================================================
// Kernel 1: per-(s,conv,m) MLP -> embedding e (128) -> h_in (64x128)
// ============================================================
__global__ __launch_bounds__(256) void embed_kernel(
    const float* __restrict__ seidel,
    const float* __restrict__ m1W1, const float* __restrict__ m1b1,
    const float* __restrict__ m1W2, const float* __restrict__ m1b2,
    const float* __restrict__ m2W1, const float* __restrict__ m2b1,
    const float* __restrict__ m2W2, const float* __restrict__ m2b2,
    const float* __restrict__ hw2, const float* __restrict__ hb2,
    float* __restrict__ hin)
{
    int combo = blockIdx.x;                 // (s*2+conv)*4 + m
    int s = combo >> 3, conv = (combo >> 2) & 1, m = combo & 3;
    const float* W1 = conv ? m2W1 : m1W1;
    const float* b1 = conv ? m2b1 : m1b1;
    const float* W2 = conv ? m2W2 : m1W2;
    const float* b2 = conv ? m2b2 : m1b2;
    __shared__ float zs[48], hbuf[128], ebuf[128];
    int tid = threadIdx.x;
    if (tid < 48) zs[tid] = seidel[s*48 + tid];
    __syncthreads();
    if (tid < 128) {
        float a = b1[m*128 + tid];
        for (int i = 0; i < 48; ++i) a += zs[i] * W1[(m*48 + i)*128 + tid];
        hbuf[tid] = fmaxf(a, 0.f);
    }
    __syncthreads();
    if (tid < 128) {
        float a = b2[m*128 + tid];
        for (int i = 0; i < 128; ++i) a += hbuf[i] * W2[(m*128 + i)*128 + tid];
        ebuf[tid] = fmaxf(a, 0.f);
    }
    __syncthreads();
    int j = tid & 127, half = tid >> 7;
    float acc[32];
    #pragma unroll
    for (int t = 0; t < 32; ++t) acc[t] = hb2[(half*32 + t)*128 + j];
    for (int i = 0; i < 128; ++i) {
        float e = ebuf[i];
        #pragma unroll
        for (int t = 0; t < 32; ++t)
            acc[t] += e * hw2[(size_t)i*8192 + (size_t)(half*32 + t)*128 + j];
    }
    #pragma unroll
    for (int t = 0; t < 32; ++t)
        hin[(size_t)combo*8192 + (size_t)(half*32 + t)*128 + j] = acc[t];
}

// ============================================================
// Kernel 2: h_fin GEMM; scatter into MFMA-tiled f16 weight table
// wtab[sc][r(8)][chunk(4)][tap(9)][co(128)][ci_local(32)] f16
// ============================================================
__global__ __launch_bounds__(256) void hfin_kernel(
    const float* __restrict__ hin, const float* __restrict__ hw1,
    const float* __restrict__ hb1, f16* __restrict__ wtab)
{
    int combo = blockIdx.y;
    int tid = threadIdx.x;
    int j = blockIdx.x*256 + tid;           // < 4608
    __shared__ float hl[64][128];
    const float* hs = hin + (size_t)combo*8192;
    for (int i = tid; i < 8192; i += 256)
        hl[i >> 7][i & 127] = hs[i];
    __syncthreads();
    float acc[64];
    float bias = hb1[j];
    #pragma unroll
    for (int a = 0; a < 64; ++a) acc[a] = bias;
    for (int k = 0; k < 128; k += 4) {
        float w0 = hw1[(size_t)(k+0)*4608 + j];
        float w1 = hw1[(size_t)(k+1)*4608 + j];
        float w2 = hw1[(size_t)(k+2)*4608 + j];
        float w3 = hw1[(size_t)(k+3)*4608 + j];
        #pragma unroll
        for (int a = 0; a < 64; ++a) {
            float4 h4 = *(const float4*)&hl[a][k];
            acc[a] += h4.x*w0 + h4.y*w1 + h4.z*w2 + h4.w*w3;
        }
    }
    int b = j/72, rem = j%72, r = rem/9, tap = rem%9;
    int s = combo >> 3, conv = (combo >> 2) & 1, m = combo & 3;
    int ci = (m & 1)*64 + b;
    int co0 = (m >> 1)*64;
    // offset = ((((sc*8+r)*4 + ci>>5)*9 + tap)*128 + co)*32 + (ci&31)
    f16* dst = wtab + ((((((size_t)(s*2 + conv)*8 + r)*4 + (ci >> 5))*9 + tap)*128 + co0)*32) + (ci & 31);
    #pragma unroll
    for (int a = 0; a < 64; ++a) dst[(size_t)a*32] = (f16)acc[a];
}

// ============================================================
// Kernel 3: transpose+cast  x f32 [sc][256h][128w] -> xt f16 [sc][128w][256h]
// ============================================================
__global__ void xpose_cast(const float* __restrict__ in, f16* __restrict__ out)
{
    __shared__ float tile[32][33];
    int sc = blockIdx.z;
    int h0 = blockIdx.y*32, w0 = blockIdx.x*32;
    int tx = threadIdx.x, ty = threadIdx.y;
    const float* src = in + ((size_t)sc*256 + h0)*128 + w0;
    #pragma unroll
    for (int i = 0; i < 4; ++i) tile[ty + i*8][tx] = src[(size_t)(ty + i*8)*128 + tx];
    __syncthreads();
    f16* dst = out + ((size_t)sc*128 + w0)*256 + h0;
    #pragma unroll
    for (int i = 0; i < 4; ++i) dst[(size_t)(ty + i*8)*256 + tx] = (f16)tile[tx][ty + i*8];
}

// ============================================================
// Kernel 5: transpose  y2t f32 [sc][128w][256h] -> out f32 [sc][256h][128w]
// ============================================================
__global__ void xpose_out(const float* __restrict__ in, float* __restrict__ out)
{
    __shared__ float tile[32][33];
    int sc = blockIdx.z;
    int w0 = blockIdx.x*32, h0 = blockIdx.y*32;   // x:4, y:8
    int tx = threadIdx.x, ty = threadIdx.y;
    const float* src = in + ((size_t)sc*128 + w0)*256 + h0;
    #pragma unroll
    for (int i = 0; i < 4; ++i) tile[ty + i*8][tx] = src[(size_t)(ty + i*8)*256 + tx];
    __syncthreads();
    float* dst = out + ((size_t)sc*256 + h0)*128 + w0;
    #pragma unroll
    for (int i = 0; i < 4; ++i) dst[(size_t)(ty + i*8)*128 + tx] = tile[tx][ty + i*8];
}

// ============================================================
// Kernel 4: MFMA LRI conv + BN + ReLU.
// grid (w=128, hh=2, s=2); 256 threads = 4 waves; block out = 128co x 128h.
// wave (wc,wh) owns 64co x 64h; frags 2x2 of 32x32; K = (chunk4, tap9, ks2)x16.
// OUT_F16=1: write f16 [s][co][128w][256h] (xt layout); else f32 same layout.
// ============================================================
template<int OUT_F16>
__global__ __launch_bounds__(256, 2) void conv_mfma(
    const f16* __restrict__ xt,
    const f16* __restrict__ wt,
    int conv,
    const float* __restrict__ bng, const float* __restrict__ bnb,
    void* __restrict__ outp)
{
    int w = blockIdx.x, hh = blockIdx.y, s = blockIdx.z;
    int hbase = hh*128;
    const f16* xs = xt + (size_t)s*128*128*256;
    const f16* wts = wt + (size_t)(s*2 + conv)*(8*4*9*128*32);

    float fsrc = (w + 0.5f)*0.0625f - 0.5f;
    fsrc = fminf(fmaxf(fsrc, 0.f), 7.f);
    int r0 = (int)fsrc;
    int r1 = min(r0 + 1, 7);
    float t = fsrc - (float)r0;

    __shared__ f16 smA[128*STRIDE];        // [co][ci32] padded rows
    __shared__ f16 smX[3*130*STRIDE];      // [dj][h'][ci32] padded rows

    int tid = threadIdx.x;
    int lane = tid & 63, wid = tid >> 6;
    int wc = wid & 1, wh = wid >> 1;
    int l31 = lane & 31, lq = lane >> 5;

    floatx16 acc[2][2];
    #pragma unroll
    for (int a = 0; a < 2; ++a)
        #pragma unroll
        for (int b = 0; b < 2; ++b) acc[a][b] = (floatx16)0.f;

    for (int chunk = 0; chunk < 4; ++chunk) {
        __syncthreads();
        // ---- stage x strips: [dj 3][h' 130][ci 32] ----
        for (int id = tid; id < 1560; id += 256) {
            int dj = id / 520;
            int r  = id - dj*520;
            int cig = r / 130;
            int hp  = r - cig*130;
            int wsg = w + dj - 1;
            half8 v = (half8)(f16)0.f;
            if (wsg >= 0 && wsg < 128) {
                int hsrc = (hbase + hp - 1) & 255;
                const f16* src = xs + ((size_t)(chunk*32 + cig*8)*128 + wsg)*256 + hsrc;
                #pragma unroll
                for (int jj = 0; jj < 8; ++jj) v[jj] = src[(size_t)jj*32768];
            }
            *(half8*)&smX[(dj*130 + hp)*STRIDE + cig*8] = v;
        }
        for (int tap = 0; tap < 9; ++tap) {
            __syncthreads();
            // ---- stage interpolated A: [co][ci32] ----
            {
                int co = tid >> 1, hf = tid & 1;
                const f16* p0 = wts + (((((size_t)r0*4 + chunk)*9 + tap)*128 + co)*32) + hf*16;
                const f16* p1 = wts + (((((size_t)r1*4 + chunk)*9 + tap)*128 + co)*32) + hf*16;
                half8 a0 = *(const half8*)p0;
                half8 a1 = *(const half8*)(p0 + 8);
                half8 b0 = *(const half8*)p1;
                half8 b1 = *(const half8*)(p1 + 8);
                half8 o0, o1;
                #pragma unroll
                for (int jj = 0; jj < 8; ++jj) {
                    float av = (float)a0[jj], bv = (float)b0[jj];
                    o0[jj] = (f16)(av + t*(bv - av));
                    float av1 = (float)a1[jj], bv1 = (float)b1[jj];
                    o1[jj] = (f16)(av1 + t*(bv1 - av1));
                }
                *(half8*)&smA[co*STRIDE + hf*16]     = o0;
                *(half8*)&smA[co*STRIDE + hf*16 + 8] = o1;
            }
            __syncthreads();
            int di = tap/3, dj = tap - di*3;
            // ---- compute: 2 K16 sub-steps x 2x2 frags ----
            #pragma unroll
            for (int ks = 0; ks < 2; ++ks) {
                half8 af[2], bf[2];
                #pragma unroll
                for (int ct = 0; ct < 2; ++ct) {
                    int co = wc*64 + ct*32 + l31;
                    af[ct] = *(const half8*)&smA[co*STRIDE + ks*16 + lq*8];
                }
                #pragma unroll
                for (int ht = 0; ht < 2; ++ht) {
                    int hl = wh*64 + ht*32 + l31;
                    bf[ht] = *(const half8*)&smX[(dj*130 + hl + di)*STRIDE + ks*16 + lq*8];
                }
                #pragma unroll
                for (int ct = 0; ct < 2; ++ct)
                    #pragma unroll
                    for (int ht = 0; ht < 2; ++ht)
                        acc[ct][ht] = __builtin_amdgcn_mfma_f32_32x32x16_f16(
                            af[ct], bf[ht], acc[ct][ht], 0, 0, 0);
            }
        }
    }

    // ---- epilogue: BN + ReLU + store (layout [s][co][w][h]) ----
    float rs = rsqrtf(1.f + 1e-5f);
    #pragma unroll
    for (int ct = 0; ct < 2; ++ct) {
        #pragma unroll
        for (int ht = 0; ht < 2; ++ht) {
            int hl = wh*64 + ht*32 + l31;
            #pragma unroll
            for (int r = 0; r < 16; ++r) {
                int co = wc*64 + ct*32 + (r & 3) + 8*(r >> 2) + 4*lq;
                float v = acc[ct][ht][r]*bng[co]*rs + bnb[co];
                v = fmaxf(v, 0.f);
                size_t off = (((size_t)(s*128 + co)*128 + w)*256) + hbase + hl;
                if (OUT_F16) ((f16*)outp)[off] = (f16)v;
                else         ((float*)outp)[off] = v;
            }
        }
    }
}

// ============================================================
extern "C" void kernel_launch(void* const* d_in, const int* in_sizes, int n_in,
                              void* d_out, int out_size, void* d_ws, size_t ws_size,
                              hipStream_t stream) {
    const float* x      = (const float*)d_in[0];
    const float* seidel = (const float*)d_in[1];
    const float* m1W1 = (const float*)d_in[2];
    const float* m1b1 = (const float*)d_in[3];
    const float* m1W2 = (const float*)d_in[4];
    const float* m1b2 = (const float*)d_in[5];
    const float* m2W1 = (const float*)d_in[6];
    const float* m2b1 = (const float*)d_in[7];
    const float* m2W2 = (const float*)d_in[8];
    const float* m2b2 = (const float*)d_in[9];
    const float* hw2  = (const float*)d_in[10];
    const float* hb2  = (const float*)d_in[11];
    const float* hw1  = (const float*)d_in[12];
    const float* hb1  = (const float*)d_in[13];
    const float* bn1g = (const float*)d_in[14];
    const float* bn1b = (const float*)d_in[15];
    const float* bn2g = (const float*)d_in[16];
    const float* bn2b = (const float*)d_in[17];
    float* outp = (float*)d_out;

    char* wsb = (char*)d_ws;
    float* hin = (float*)wsb;                                   // 524288 B
    f16*   wtab = (f16*)(wsb + 524288);                         // 9437184 B
    f16*   xt   = (f16*)(wsb + 524288 + 9437184);               // 16777216 B
    f16*   y1t  = (f16*)(wsb + 524288 + 9437184 + 16777216);    // 16777216 B
    float* y2t  = (float*)(wsb + 524288 + 9437184 + 2*16777216); // 33554432 B

    embed_kernel<<<16, 256, 0, stream>>>(seidel, m1W1, m1b1, m1W2, m1b2,
                                         m2W1, m2b1, m2W2, m2b2, hw2, hb2, hin);
    hfin_kernel<<<dim3(18, 16), 256, 0, stream>>>(hin, hw1, hb1, wtab);
    xpose_cast<<<dim3(4, 8, 256), dim3(32, 8), 0, stream>>>(x, xt);
    conv_mfma<1><<<dim3(128, 2, 2), 256, 0, stream>>>(xt, wtab, 0, bn1g, bn1b, (void*)y1t);
    conv_mfma<0><<<dim3(128, 2, 2), 256, 0, stream>>>(y1t, wtab, 1, bn2g, bn2b, (void*)y2t);
    xpose_out<<<dim3(4, 8, 256), dim3(32, 8), 0, stream>>>(y2t, outp);
}

// Round 3
// 174.980 us; speedup vs baseline: 4.8745x; 1.6471x over previous
//
#include <hip/hip_runtime.h>
#include <hip/hip_bf16.h>

typedef _Float16 f16;
typedef _Float16 half8 __attribute__((ext_vector_type(8)));
typedef _Float16 half4_t __attribute__((ext_vector_type(4)));
typedef float floatx16 __attribute__((ext_vector_type(16)));

// ============================================================
// Kernel 1a: per-(s,conv,m) MLP -> embedding e (128)
// ============================================================
__global__ __launch_bounds__(256) void embed_a(
    const float* __restrict__ seidel,
    const float* __restrict__ m1W1, const float* __restrict__ m1b1,
    const float* __restrict__ m1W2, const float* __restrict__ m1b2,
    const float* __restrict__ m2W1, const float* __restrict__ m2b1,
    const float* __restrict__ m2W2, const float* __restrict__ m2b2,
    float* __restrict__ eout)
{
    int combo = blockIdx.x;                 // (s*2+conv)*4 + m
    int s = combo >> 3, conv = (combo >> 2) & 1, m = combo & 3;
    const float* W1 = conv ? m2W1 : m1W1;
    const float* b1 = conv ? m2b1 : m1b1;
    const float* W2 = conv ? m2W2 : m1W2;
    const float* b2 = conv ? m2b2 : m1b2;
    __shared__ float zs[48], hbuf[128];
    int tid = threadIdx.x;
    if (tid < 48) zs[tid] = seidel[s*48 + tid];
    __syncthreads();
    if (tid < 128) {
        float a = b1[m*128 + tid];
        for (int i = 0; i < 48; ++i) a += zs[i] * W1[(m*48 + i)*128 + tid];
        hbuf[tid] = fmaxf(a, 0.f);
    }
    __syncthreads();
    if (tid < 128) {
        float a = b2[m*128 + tid];
        for (int i = 0; i < 128; ++i) a += hbuf[i] * W2[(m*128 + i)*128 + tid];
        eout[combo*128 + tid] = fmaxf(a, 0.f);
    }
}

// ============================================================
// Kernel 1b: h_in = e @ hyp_w2 + hyp_b2.  grid (32 jtiles, 16 combos)
// ============================================================
__global__ __launch_bounds__(256) void embed_b(
    const float* __restrict__ eout, const float* __restrict__ hw2,
    const float* __restrict__ hb2, float* __restrict__ hin)
{
    int combo = blockIdx.y;
    int j = blockIdx.x*256 + threadIdx.x;   // < 8192
    __shared__ float es[128];
    if (threadIdx.x < 128) es[threadIdx.x] = eout[combo*128 + threadIdx.x];
    __syncthreads();
    float a = hb2[j];
    for (int i = 0; i < 128; ++i) a += es[i] * hw2[(size_t)i*8192 + j];
    hin[(size_t)combo*8192 + j] = a;
}

// ============================================================
// Kernel 2a: transpose hw1 [128 k][4608 j] -> hw1t [4608 j][128 k]
// grid (144, 4), block (32,8)
// ============================================================
__global__ void hw1t_kernel(const float* __restrict__ in, float* __restrict__ out)
{
    __shared__ float tile[32][33];
    int j0 = blockIdx.x*32, k0 = blockIdx.y*32;
    int tx = threadIdx.x, ty = threadIdx.y;
    #pragma unroll
    for (int i = 0; i < 4; ++i) tile[ty + i*8][tx] = in[(size_t)(k0 + ty + i*8)*4608 + j0 + tx];
    __syncthreads();
    #pragma unroll
    for (int i = 0; i < 4; ++i) out[(size_t)(j0 + ty + i*8)*128 + k0 + tx] = tile[tx][ty + i*8];
}

// ============================================================
// Kernel 2b: h_fin tile GEMM + coalesced scatter into wtab.
// grid (72 = r*9+tap, 16 combos), 256 threads.
// C[a 64][b 64] = hin[a][k] @ hw1t[j(b)][k] + bias; j = b*72 + r*9 + tap
// wtab [sc][r 8][chunk 4][tap 9][co 128][ci 32] f16
// ============================================================
__global__ __launch_bounds__(256) void hfin2_kernel(
    const float* __restrict__ hin, const float* __restrict__ hw1t,
    const float* __restrict__ hb1, f16* __restrict__ wtab)
{
    int c72 = blockIdx.x;
    int combo = blockIdx.y;
    int r = c72 / 9, tap = c72 - r*9;
    int s = combo >> 3, conv = (combo >> 2) & 1, m = combo & 3;
    __shared__ float hl[64][132];
    __shared__ float wt[64][132];
    __shared__ f16 ct[64][72];
    int tid = threadIdx.x;
    const float4* hsrc = (const float4*)(hin + (size_t)combo*8192);
    for (int i = tid; i < 2048; i += 256) {
        int a = i >> 5, kq = i & 31;
        *(float4*)&hl[a][kq*4] = hsrc[i];
    }
    for (int i = tid; i < 2048; i += 256) {
        int b = i >> 5, kq = i & 31;
        *(float4*)&wt[b][kq*4] = *(const float4*)(hw1t + (size_t)(b*72 + c72)*128 + kq*4);
    }
    __syncthreads();
    int ta = tid >> 4, tb = tid & 15;
    int a0 = ta*4, b0 = tb*4;
    float acc[4][4] = {};
    #pragma unroll 4
    for (int k4 = 0; k4 < 32; ++k4) {
        float4 A[4], B[4];
        #pragma unroll
        for (int i = 0; i < 4; ++i) A[i] = *(const float4*)&hl[a0 + i][k4*4];
        #pragma unroll
        for (int i = 0; i < 4; ++i) B[i] = *(const float4*)&wt[b0 + i][k4*4];
        #pragma unroll
        for (int i = 0; i < 4; ++i)
            #pragma unroll
            for (int j2 = 0; j2 < 4; ++j2)
                acc[i][j2] += A[i].x*B[j2].x + A[i].y*B[j2].y + A[i].z*B[j2].z + A[i].w*B[j2].w;
    }
    float bj[4];
    #pragma unroll
    for (int j2 = 0; j2 < 4; ++j2) bj[j2] = hb1[(b0 + j2)*72 + c72];
    #pragma unroll
    for (int i = 0; i < 4; ++i) {
        half4_t v;
        #pragma unroll
        for (int j2 = 0; j2 < 4; ++j2) v[j2] = (f16)(acc[i][j2] + bj[j2]);
        *(half4_t*)&ct[a0 + i][b0] = v;
    }
    __syncthreads();
    // write out: 128 runs of 64 B; each thread 32 B
    {
        int run = tid >> 1, hh = tid & 1;
        int a = run & 63, ch = run >> 6;
        int chunk = (m & 1)*2 + ch;
        int co = (m >> 1)*64 + a;
        size_t base = ((((size_t)(s*2 + conv)*8 + r)*4 + chunk)*9 + tap)*128 + co;
        f16* dst = wtab + base*32 + hh*16;
        const f16* src = &ct[a][ch*32 + hh*16];
        *(half8*)(dst)     = *(const half8*)(src);
        *(half8*)(dst + 8) = *(const half8*)(src + 8);
    }
}

// ============================================================
// Kernel 3: x [s][c][h][w] f32 -> xt [s][w][h][c] f16. grid (256 h, 2 s)
// ============================================================
__global__ __launch_bounds__(256) void xpose_cast2(
    const float* __restrict__ in, f16* __restrict__ out)
{
    __shared__ f16 tileT[128*136];   // [w][c], rows padded to 136
    int h = blockIdx.x, s = blockIdx.y;
    int tid = threadIdx.x;
    int cg = tid >> 5, q2 = tid & 31;
    const float* src = in + (size_t)s*4194304 + (size_t)h*128;
    for (int pass = 0; pass < 16; ++pass) {
        int c = pass*8 + cg;
        float4 v = *(const float4*)(src + (size_t)c*32768 + q2*4);
        tileT[(q2*4 + 0)*136 + c] = (f16)v.x;
        tileT[(q2*4 + 1)*136 + c] = (f16)v.y;
        tileT[(q2*4 + 2)*136 + c] = (f16)v.z;
        tileT[(q2*4 + 3)*136 + c] = (f16)v.w;
    }
    __syncthreads();
    int ww = tid >> 1, hf = tid & 1;
    const f16* srcT = &tileT[ww*136 + hf*64];
    f16* dst = out + (((size_t)(s*128 + ww)*256 + h)*128) + hf*64;
    #pragma unroll
    for (int i = 0; i < 8; ++i)
        *(float4*)(dst + i*8) = *(const float4*)(srcT + i*8);
}

// ============================================================
// Kernel 5: y2t [s*co][w][h] f32 -> out [s*co][h][w] f32
// ============================================================
__global__ void xpose_out(const float* __restrict__ in, float* __restrict__ out)
{
    __shared__ float tile[32][33];
    int sc = blockIdx.z;
    int w0 = blockIdx.x*32, h0 = blockIdx.y*32;
    int tx = threadIdx.x, ty = threadIdx.y;
    const float* src = in + ((size_t)sc*128 + w0)*256 + h0;
    #pragma unroll
    for (int i = 0; i < 4; ++i) tile[ty + i*8][tx] = src[(size_t)(ty + i*8)*256 + tx];
    __syncthreads();
    float* dst = out + ((size_t)sc*256 + h0)*128 + w0;
    #pragma unroll
    for (int i = 0; i < 4; ++i) dst[(size_t)(ty + i*8)*128 + tx] = tile[tx][ty + i*8];
}

// ============================================================
// Kernel 4: MFMA LRI conv + BN + ReLU.
// xin: [s][w 128][h 256][c 128] f16. grid (w 128, hh 2, s 2), 256 thr.
// Block out = 128co x 128h; wave (wc,wh) = 64co x 64h; 2x2 frags of 32x32.
// OUT_F16=1: write f16 [s][w][h][co] via LDS tile (coalesced).
// OUT_F16=0: write f32 [s][co][w][h] direct (line-cooperative).
// ============================================================
template<int OUT_F16>
__global__ __launch_bounds__(256, 2) void conv_mfma2(
    const f16* __restrict__ xin,
    const f16* __restrict__ wtab,
    int conv,
    const float* __restrict__ bng, const float* __restrict__ bnb,
    void* __restrict__ outp)
{
    int w = blockIdx.x, hh = blockIdx.y, s = blockIdx.z;
    int hbase = hh*128;
    const f16* xs  = xin  + (size_t)s*4194304;
    const f16* wts = wtab + (size_t)(s*2 + conv)*1179648;

    float fsrc = (w + 0.5f)*0.0625f - 0.5f;
    fsrc = fminf(fmaxf(fsrc, 0.f), 7.f);
    int r0 = (int)fsrc;
    int r1 = min(r0 + 1, 7);
    float t = fsrc - (float)r0;

    __shared__ __align__(16) char sbuf[51712];
    f16* smA   = (f16*)sbuf;                 // [2][128*40]
    f16* smX   = (f16*)(sbuf + 20480);       // [3*130*40]
    f16* otile = (f16*)sbuf;                 // epilogue [128][136]

    int tid = threadIdx.x;
    int lane = tid & 63, wid = tid >> 6;
    int wc = wid & 1, wh = wid >> 1;
    int l31 = lane & 31, lq = lane >> 5;
    int sco = tid >> 1, shf = tid & 1;       // smA staging coords

    floatx16 acc[2][2];
    #pragma unroll
    for (int a = 0; a < 2; ++a)
        #pragma unroll
        for (int b = 0; b < 2; ++b) acc[a][b] = (floatx16)0.f;

    for (int chunk = 0; chunk < 4; ++chunk) {
        __syncthreads();
        // ---- stage x strips: smX[dj*130+hp][ci32], 4 half8 per (dj,hp) ----
        for (int id = tid; id < 1560; id += 256) {
            int dj = id / 520;
            int r2 = id - dj*520;
            int hp = r2 >> 2, cig = r2 & 3;
            int wsg = w + dj - 1;
            half8 v = {};
            if (wsg >= 0 && wsg < 128) {
                int hsrc = (hbase + hp - 1) & 255;
                v = *(const half8*)(xs + ((size_t)wsg*256 + hsrc)*128 + chunk*32 + cig*8);
            }
            *(half8*)&smX[(dj*130 + hp)*40 + cig*8] = v;
        }
        // ---- stage A for tap 0 into buf 0 ----
        {
            const f16* p0 = wts + ((((size_t)r0*4 + chunk)*9 + 0)*128 + sco)*32 + shf*16;
            const f16* p1 = wts + ((((size_t)r1*4 + chunk)*9 + 0)*128 + sco)*32 + shf*16;
            half8 a0 = *(const half8*)p0, a1 = *(const half8*)(p0 + 8);
            half8 b0 = *(const half8*)p1, b1 = *(const half8*)(p1 + 8);
            half8 o0, o1;
            #pragma unroll
            for (int jj = 0; jj < 8; ++jj) {
                float av = (float)a0[jj], bv = (float)b0[jj];
                o0[jj] = (f16)(av + t*(bv - av));
                float av1 = (float)a1[jj], bv1 = (float)b1[jj];
                o1[jj] = (f16)(av1 + t*(bv1 - av1));
            }
            *(half8*)&smA[sco*40 + shf*16]     = o0;
            *(half8*)&smA[sco*40 + shf*16 + 8] = o1;
        }
        __syncthreads();
        for (int tap = 0; tap < 9; ++tap) {
            const f16* abuf = smA + (tap & 1)*5120;
            if (tap < 8) {   // stage next tap into other buffer
                f16* dbuf = smA + ((tap + 1) & 1)*5120;
                int tp = tap + 1;
                const f16* p0 = wts + ((((size_t)r0*4 + chunk)*9 + tp)*128 + sco)*32 + shf*16;
                const f16* p1 = wts + ((((size_t)r1*4 + chunk)*9 + tp)*128 + sco)*32 + shf*16;
                half8 a0 = *(const half8*)p0, a1 = *(const half8*)(p0 + 8);
                half8 b0 = *(const half8*)p1, b1 = *(const half8*)(p1 + 8);
                half8 o0, o1;
                #pragma unroll
                for (int jj = 0; jj < 8; ++jj) {
                    float av = (float)a0[jj], bv = (float)b0[jj];
                    o0[jj] = (f16)(av + t*(bv - av));
                    float av1 = (float)a1[jj], bv1 = (float)b1[jj];
                    o1[jj] = (f16)(av1 + t*(bv1 - av1));
                }
                *(half8*)&dbuf[sco*40 + shf*16]     = o0;
                *(half8*)&dbuf[sco*40 + shf*16 + 8] = o1;
            }
            int di = tap/3, dj = tap - di*3;
            #pragma unroll
            for (int ks = 0; ks < 2; ++ks) {
                half8 af[2], bf[2];
                #pragma unroll
                for (int ct2 = 0; ct2 < 2; ++ct2)
                    af[ct2] = *(const half8*)&abuf[(wc*64 + ct2*32 + l31)*40 + ks*16 + lq*8];
                #pragma unroll
                for (int ht = 0; ht < 2; ++ht)
                    bf[ht] = *(const half8*)&smX[(dj*130 + wh*64 + ht*32 + l31 + di)*40 + ks*16 + lq*8];
                #pragma unroll
                for (int ct2 = 0; ct2 < 2; ++ct2)
                    #pragma unroll
                    for (int ht = 0; ht < 2; ++ht)
                        acc[ct2][ht] = __builtin_amdgcn_mfma_f32_32x32x16_f16(
                            af[ct2], bf[ht], acc[ct2][ht], 0, 0, 0);
            }
            __syncthreads();
        }
    }

    float rs = rsqrtf(1.f + 1e-5f);
    if (OUT_F16) {
        // BN+ReLU -> otile[h][co] -> linear coalesced store [s][w][h][co]
        #pragma unroll
        for (int ct2 = 0; ct2 < 2; ++ct2) {
            #pragma unroll
            for (int ht = 0; ht < 2; ++ht) {
                int hrow = wh*64 + ht*32 + l31;
                #pragma unroll
                for (int rq = 0; rq < 4; ++rq) {
                    int cb = wc*64 + ct2*32 + rq*8 + lq*4;
                    float4 g4 = *(const float4*)&bng[cb];
                    float4 b4 = *(const float4*)&bnb[cb];
                    half4_t v;
                    v[0] = (f16)fmaxf(acc[ct2][ht][rq*4 + 0]*g4.x*rs + b4.x, 0.f);
                    v[1] = (f16)fmaxf(acc[ct2][ht][rq*4 + 1]*g4.y*rs + b4.y, 0.f);
                    v[2] = (f16)fmaxf(acc[ct2][ht][rq*4 + 2]*g4.z*rs + b4.z, 0.f);
                    v[3] = (f16)fmaxf(acc[ct2][ht][rq*4 + 3]*g4.w*rs + b4.w, 0.f);
                    *(half4_t*)&otile[hrow*136 + cb] = v;
                }
            }
        }
        __syncthreads();
        f16* yout = (f16*)outp + ((size_t)(s*128 + w)*256 + hbase)*128;
        {
            int hrow = tid >> 1, hf = tid & 1;
            const f16* srcT = &otile[hrow*136 + hf*64];
            f16* d = yout + hrow*128 + hf*64;
            #pragma unroll
            for (int i = 0; i < 8; ++i)
                *(float4*)(d + i*8) = *(const float4*)(srcT + i*8);
        }
    } else {
        // f32 direct store to [s][co][w][h] (32-lane h-contiguous per reg)
        #pragma unroll
        for (int ct2 = 0; ct2 < 2; ++ct2) {
            #pragma unroll
            for (int ht = 0; ht < 2; ++ht) {
                int hrow = wh*64 + ht*32 + l31;
                #pragma unroll
                for (int r = 0; r < 16; ++r) {
                    int co = wc*64 + ct2*32 + (r & 3) + 8*(r >> 2) + 4*lq;
                    float v = fmaxf(acc[ct2][ht][r]*bng[co]*rs + bnb[co], 0.f);
                    ((float*)outp)[((size_t)(s*128 + co)*128 + w)*256 + hbase + hrow] = v;
                }
            }
        }
    }
}

// ============================================================
extern "C" void kernel_launch(void* const* d_in, const int* in_sizes, int n_in,
                              void* d_out, int out_size, void* d_ws, size_t ws_size,
                              hipStream_t stream) {
    const float* x      = (const float*)d_in[0];
    const float* seidel = (const float*)d_in[1];
    const float* m1W1 = (const float*)d_in[2];
    const float* m1b1 = (const float*)d_in[3];
    const float* m1W2 = (const float*)d_in[4];
    const float* m1b2 = (const float*)d_in[5];
    const float* m2W1 = (const float*)d_in[6];
    const float* m2b1 = (const float*)d_in[7];
    const float* m2W2 = (const float*)d_in[8];
    const float* m2b2 = (const float*)d_in[9];
    const float* hw2  = (const float*)d_in[10];
    const float* hb2  = (const float*)d_in[11];
    const float* hw1  = (const float*)d_in[12];
    const float* hb1  = (const float*)d_in[13];
    const float* bn1g = (const float*)d_in[14];
    const float* bn1b = (const float*)d_in[15];
    const float* bn2g = (const float*)d_in[16];
    const float* bn2b = (const float*)d_in[17];
    float* outp = (float*)d_out;

    char* wsb = (char*)d_ws;
    float* hin  = (float*)wsb;                          // 524288 B
    f16*   wtab = (f16*)(wsb + 524288);                 // 9437184 B
    f16*   xt   = (f16*)(wsb + 9961472);                // 16777216 B
    f16*   y1t  = (f16*)(wsb + 26738688);               // 16777216 B
    float* y2t  = (float*)(wsb + 43515904);             // 33554432 B
    float* eout = (float*)xt;                           // 8 KB, consumed before xt written
    float* hw1t = y2t;                                  // 2359296 B, consumed before y2t written

    embed_a<<<16, 256, 0, stream>>>(seidel, m1W1, m1b1, m1W2, m1b2,
                                    m2W1, m2b1, m2W2, m2b2, eout);
    embed_b<<<dim3(32, 16), 256, 0, stream>>>(eout, hw2, hb2, hin);
    hw1t_kernel<<<dim3(144, 4), dim3(32, 8), 0, stream>>>(hw1, hw1t);
    hfin2_kernel<<<dim3(72, 16), 256, 0, stream>>>(hin, hw1t, hb1, wtab);
    xpose_cast2<<<dim3(256, 2), 256, 0, stream>>>(x, xt);
    conv_mfma2<1><<<dim3(128, 2, 2), 256, 0, stream>>>(xt, wtab, 0, bn1g, bn1b, (void*)y1t);
    conv_mfma2<0><<<dim3(128, 2, 2), 256, 0, stream>>>(y1t, wtab, 1, bn2g, bn2b, (void*)y2t);
    xpose_out<<<dim3(4, 8, 256), dim3(32, 8), 0, stream>>>(y2t, outp);
}